// Round 5
// baseline (249.856 us; speedup 1.0000x reference)
//
#include <hip/hip_runtime.h>
#include <math.h>

// Problem constants (fixed by the reference): Q=4096 queries, N=65536 train, D=32.
#define QN 4096
#define NN 65536
#define DD 32

#define GX 16
#define GY 128
#define NBLK (GX * GY)   // 2048 blocks

typedef __attribute__((ext_vector_type(8))) _Float16 half8;
typedef __attribute__((ext_vector_type(4))) _Float16 half4v;
typedef __attribute__((ext_vector_type(4))) float floatx4;

#define LOG2E 1.4426950408889634f
#define LN2   0.6931471805599453f
#define HALF_D_LOG_2PI 29.40603306254953f   // 16 * ln(2*pi)

// exp2-in-MFMA scaling: A = x*log2(e)*2^11, B = y*2^12, C = 127*2^23.
// MFMA then emits v = (127 + x.y*log2e)*2^23 == the float bit pattern of
// 2^(x.y*log2e) under the linear-mantissa approximation. Epilogue per
// element: clamp -> cvt_i32 -> bitcast -> fmac (3 full-rate VALU ops, no
// transcendental).
#define ASCALE 2954.6394357789634f   // log2(e) * 2048
#define BSCALE 4096.0f               // 2^12
#define BIAS_F 1065353216.0f         // 127 * 2^23
#define CAPF   1585446912.0f         // (127+62) * 2^23  (no legit term > 2^57)
#define CENTER 0.970656f             // centers the +6.1% one-sided approx error

__device__ __forceinline__ float fexp_term(float v) {
    // v_med3_f32 (clamp to [0, CAPF]) + v_cvt_i32_f32 + free bitcast
    v = __builtin_fminf(__builtin_fmaxf(v, 0.0f), CAPF);
    return __int_as_float((int)v);
}

// ---------------------------------------------------------------------------
// Workspace layout (bytes):
//   Xh   @ 0        : QN*DD*2 = 262144   (_Float16, X * ASCALE)
//   Xth  @ 262144   : NN*DD*2 = 4194304  (_Float16, X_train * BSCALE)
//   c    @ 4456448  : NN*4    = 262144   (CENTER * w_j * exp(-||y_j||^2/2))
//   qn   @ 4718592  : QN*4    = 16384    (||x_i||^2 / 2, nat units)
//   S    @ 4734976  : QN*4    = 16384    (zeroed by prep_all)
//   swp  @ 4751360  : 64*4    = 256      (per-block partial sums of w)
//   done @ 4751616  : 4                  (block-completion counter)
// ---------------------------------------------------------------------------

// Fused prep: blocks [0,128) convert X (+ zero S/done), [128,2176) convert
// X_train + c, [2176,2240) reduce sum(w) into per-block partials.
__global__ __launch_bounds__(256) void prep_all(
    const float* __restrict__ X, const float* __restrict__ Xt,
    const float* __restrict__ w, _Float16* __restrict__ Xh,
    float* __restrict__ qn, _Float16* __restrict__ Xth,
    float* __restrict__ c, float* __restrict__ S,
    float* __restrict__ swp, unsigned* __restrict__ done) {
    const int b = blockIdx.x;
    if (b < 128) {                       // ---- prep X: QN rows, 8 lanes/row
        int tid  = b * 256 + threadIdx.x;
        int row  = tid >> 3;
        int part = tid & 7;
        const float4 v = ((const float4*)X)[row * 8 + part];
        float nrm = v.x * v.x + v.y * v.y + v.z * v.z + v.w * v.w;
        nrm += __shfl_xor(nrm, 1);
        nrm += __shfl_xor(nrm, 2);
        nrm += __shfl_xor(nrm, 4);
        half4v h = { (_Float16)(v.x * ASCALE), (_Float16)(v.y * ASCALE),
                     (_Float16)(v.z * ASCALE), (_Float16)(v.w * ASCALE) };
        *(half4v*)(Xh + row * DD + part * 4) = h;
        if (part == 0) qn[row] = 0.5f * nrm;
        if (tid < QN) S[tid] = 0.f;      // fused zeroing of S
        if (tid == QN) *done = 0u;
    } else if (b < 2176) {               // ---- prep X_train: NN rows
        int tid  = (b - 128) * 256 + threadIdx.x;
        int row  = tid >> 3;
        int part = tid & 7;
        const float4 v = ((const float4*)Xt)[row * 8 + part];
        float nrm = v.x * v.x + v.y * v.y + v.z * v.z + v.w * v.w;
        nrm += __shfl_xor(nrm, 1);
        nrm += __shfl_xor(nrm, 2);
        nrm += __shfl_xor(nrm, 4);
        half4v h = { (_Float16)(v.x * BSCALE), (_Float16)(v.y * BSCALE),
                     (_Float16)(v.z * BSCALE), (_Float16)(v.w * BSCALE) };
        *(half4v*)(Xth + row * DD + part * 4) = h;
        if (part == 0)
            c[row] = w[row] * __builtin_amdgcn_exp2f(-0.5f * LOG2E * nrm) * CENTER;
    } else {                             // ---- sum(w) partials: 64 blocks
        int bid = b - 2176;
        float v = 0.f;
        for (int i = bid * 256 + threadIdx.x; i < NN; i += 64 * 256)
            v += w[i];
        #pragma unroll
        for (int o = 1; o < 64; o <<= 1) v += __shfl_xor(v, o);
        __shared__ float red[4];
        if ((threadIdx.x & 63) == 0) red[threadIdx.x >> 6] = v;
        __syncthreads();
        if (threadIdx.x == 0) swp[bid] = red[0] + red[1] + red[2] + red[3];
    }
}

// Main fused kernel: per wave, 64 queries x strip of 512 train points,
// n-loop unrolled x2. Grid (16,128), block 256 = 4 waves. Last block to
// retire computes the final log-normalized output (R3-proven protocol).
__global__ __launch_bounds__(256) void kde_main(
    const _Float16* __restrict__ Xh, const _Float16* __restrict__ Xth,
    const float* __restrict__ c, float* __restrict__ S,
    const float* __restrict__ qn, const float* __restrict__ swp,
    unsigned* __restrict__ done, float* __restrict__ out) {
    const int lane   = threadIdx.x & 63;
    const int wave   = threadIdx.x >> 6;
    const int quad   = lane >> 4;
    const int l16    = lane & 15;
    const int m_base = blockIdx.x * 256 + wave * 64;
    const int n_beg  = blockIdx.y * 512;

    // A fragments: 4 tiles of 16 queries, resident for the whole strip.
    half8 a0 = *(const half8*)(Xh + (m_base +  0 + l16) * DD + quad * 8);
    half8 a1 = *(const half8*)(Xh + (m_base + 16 + l16) * DD + quad * 8);
    half8 a2 = *(const half8*)(Xh + (m_base + 32 + l16) * DD + quad * 8);
    half8 a3 = *(const half8*)(Xh + (m_base + 48 + l16) * DD + quad * 8);

    float s0[4][4] = {};
    float s1[4][4] = {};
    const floatx4 cbias = {BIAS_F, BIAS_F, BIAS_F, BIAS_F};

    const _Float16* bp = Xth + (size_t)(n_beg + l16) * DD + quad * 8;
    const float*    cp = c + n_beg + l16;

    for (int it = 0; it < 16; ++it) {
        half8 b0 = *(const half8*)bp;
        half8 b1 = *(const half8*)(bp + 16 * DD);
        float c0 = cp[0];
        float c1 = cp[16];
        bp += 32 * DD;
        cp += 32;

        // MFMA emits (g+127)*2^23 directly (bias via C operand).
        floatx4 g00 = __builtin_amdgcn_mfma_f32_16x16x32_f16(a0, b0, cbias, 0, 0, 0);
        floatx4 g10 = __builtin_amdgcn_mfma_f32_16x16x32_f16(a0, b1, cbias, 0, 0, 0);
        floatx4 g01 = __builtin_amdgcn_mfma_f32_16x16x32_f16(a1, b0, cbias, 0, 0, 0);
        floatx4 g11 = __builtin_amdgcn_mfma_f32_16x16x32_f16(a1, b1, cbias, 0, 0, 0);
        floatx4 g02 = __builtin_amdgcn_mfma_f32_16x16x32_f16(a2, b0, cbias, 0, 0, 0);
        floatx4 g12 = __builtin_amdgcn_mfma_f32_16x16x32_f16(a2, b1, cbias, 0, 0, 0);
        floatx4 g03 = __builtin_amdgcn_mfma_f32_16x16x32_f16(a3, b0, cbias, 0, 0, 0);
        floatx4 g13 = __builtin_amdgcn_mfma_f32_16x16x32_f16(a3, b1, cbias, 0, 0, 0);

        #pragma unroll
        for (int r = 0; r < 4; ++r) {
            s0[0][r] += c0 * fexp_term(g00[r]);
            s1[0][r] += c1 * fexp_term(g10[r]);
            s0[1][r] += c0 * fexp_term(g01[r]);
            s1[1][r] += c1 * fexp_term(g11[r]);
            s0[2][r] += c0 * fexp_term(g02[r]);
            s1[2][r] += c1 * fexp_term(g12[r]);
            s0[3][r] += c0 * fexp_term(g03[r]);
            s1[3][r] += c1 * fexp_term(g13[r]);
        }
    }

    // Reduce over the 16 columns (lanes sharing the same quad), then atomic.
    #pragma unroll
    for (int t = 0; t < 4; ++t) {
        #pragma unroll
        for (int r = 0; r < 4; ++r) {
            float v = (t == 0 ? s0[0][r] + s1[0][r] :
                       t == 1 ? s0[1][r] + s1[1][r] :
                       t == 2 ? s0[2][r] + s1[2][r] :
                                s0[3][r] + s1[3][r]);
            v += __shfl_xor(v, 1);
            v += __shfl_xor(v, 2);
            v += __shfl_xor(v, 4);
            v += __shfl_xor(v, 8);
            if (l16 == 0)
                atomicAdd(&S[m_base + t * 16 + quad * 4 + r], v);
        }
    }

    // -------- fused finalize: last block to retire does the epilogue -------
    __threadfence();
    __shared__ int last;
    if (threadIdx.x == 0) {
        unsigned cnt = atomicAdd(done, 1u);
        last = (cnt == NBLK - 1) ? 1 : 0;
    }
    __syncthreads();
    if (last) {
        __threadfence();
        float sw = 0.f;                      // 64 partials from prep_all
        #pragma unroll
        for (int k = 0; k < 64; ++k) sw += swp[k];
        float lsw = __builtin_amdgcn_logf(sw) * LN2;   // v_log_f32 = log2
        for (int i = threadIdx.x; i < QN; i += 256) {
            float Sv = __hip_atomic_load(&S[i], __ATOMIC_RELAXED,
                                         __HIP_MEMORY_SCOPE_AGENT);
            out[i] = __builtin_amdgcn_logf(Sv) * LN2 - qn[i]
                     - HALF_D_LOG_2PI - lsw;
        }
    }
}

extern "C" void kernel_launch(void* const* d_in, const int* in_sizes, int n_in,
                              void* d_out, int out_size, void* d_ws, size_t ws_size,
                              hipStream_t stream) {
    const float* X  = (const float*)d_in[0];
    const float* Xt = (const float*)d_in[1];
    const float* w  = (const float*)d_in[2];
    float* out = (float*)d_out;

    char* ws = (char*)d_ws;
    _Float16* Xh   = (_Float16*)(ws);
    _Float16* Xth  = (_Float16*)(ws + 262144);
    float*    c    = (float*)(ws + 4456448);
    float*    qn   = (float*)(ws + 4718592);
    float*    S    = (float*)(ws + 4734976);
    float*    swp  = (float*)(ws + 4751360);
    unsigned* done = (unsigned*)(ws + 4751616);

    prep_all<<<2240, 256, 0, stream>>>(X, Xt, w, Xh, qn, Xth, c, S, swp, done);
    kde_main<<<dim3(GX, GY), 256, 0, stream>>>(Xh, Xth, c, S, qn, swp, done, out);
}

// Round 6
// 118.504 us; speedup vs baseline: 2.1084x; 2.1084x over previous
//
#include <hip/hip_runtime.h>
#include <math.h>

// Problem constants (fixed by the reference): Q=4096 queries, N=65536 train, D=32.
#define QN 4096
#define NN 65536
#define DD 32

typedef __attribute__((ext_vector_type(8))) _Float16 half8;
typedef __attribute__((ext_vector_type(4))) _Float16 half4v;
typedef __attribute__((ext_vector_type(4))) float floatx4;

#define LOG2E 1.4426950408889634f
#define HALF_D_LOG_2PI 29.40603306254953f   // 16 * ln(2*pi)

// exp2-in-MFMA scaling: A = x*log2(e)*2^11, B = y*2^12, C = 127*2^23.
// The MFMA emits v = (127 + x.y*log2e)*2^23 == the float bit pattern of
// 2^(x.y*log2e) under the linear-mantissa approximation (max rel err 6.1%,
// one-sided; CENTER recenters it). Per element: max, min, cvt_i32, fmac —
// 4 full-rate VALU ops, no transcendental. Validated in R5 (absmax 0.25).
#define ASCALE 2954.6394357789634f   // log2(e) * 2048
#define BSCALE 4096.0f               // 2^12
#define BIAS_F 1065353216.0f         // 127 * 2^23
#define CAPF   1585446912.0f         // (127+62) * 2^23  (no legit term > 2^57)
#define CENTER 0.970656f             // centers the one-sided approx error

__device__ __forceinline__ float fexp_term(float v) {
    v = __builtin_fminf(__builtin_fmaxf(v, 0.0f), CAPF);
    return __int_as_float((int)v);
}

// ---------------------------------------------------------------------------
// Workspace layout (bytes):
//   Xh    @ 0        : QN*DD*2 = 262144   (_Float16, X * ASCALE)
//   Xth   @ 262144   : NN*DD*2 = 4194304  (_Float16, X_train * BSCALE)
//   c     @ 4456448  : NN*4    = 262144   (CENTER * w_j * exp(-||y_j||^2/2))
//   qn    @ 4718592  : QN*4    = 16384    (||x_i||^2 / 2, nat units)
//   S     @ 4734976  : QN*4    = 16384    (memset 0 each call)
//   sumw  @ 4751360  : 4
// ---------------------------------------------------------------------------

// Fused prep: blocks [0,128) convert X, [128,2176) convert X_train + c,
// [2176,2240) reduce sum(w). No fences, no cross-block protocol (R5 lesson).
__global__ __launch_bounds__(256) void prep_all(
    const float* __restrict__ X, const float* __restrict__ Xt,
    const float* __restrict__ w, _Float16* __restrict__ Xh,
    float* __restrict__ qn, _Float16* __restrict__ Xth,
    float* __restrict__ c, float* __restrict__ sumw) {
    const int b = blockIdx.x;
    if (b < 128) {                       // ---- prep X: QN rows, 8 lanes/row
        int tid  = b * 256 + threadIdx.x;
        int row  = tid >> 3;
        int part = tid & 7;
        const float4 v = ((const float4*)X)[row * 8 + part];
        float nrm = v.x * v.x + v.y * v.y + v.z * v.z + v.w * v.w;
        nrm += __shfl_xor(nrm, 1);
        nrm += __shfl_xor(nrm, 2);
        nrm += __shfl_xor(nrm, 4);
        half4v h = { (_Float16)(v.x * ASCALE), (_Float16)(v.y * ASCALE),
                     (_Float16)(v.z * ASCALE), (_Float16)(v.w * ASCALE) };
        *(half4v*)(Xh + row * DD + part * 4) = h;
        if (part == 0) qn[row] = 0.5f * nrm;
    } else if (b < 2176) {               // ---- prep X_train: NN rows
        int tid  = (b - 128) * 256 + threadIdx.x;
        int row  = tid >> 3;
        int part = tid & 7;
        const float4 v = ((const float4*)Xt)[row * 8 + part];
        float nrm = v.x * v.x + v.y * v.y + v.z * v.z + v.w * v.w;
        nrm += __shfl_xor(nrm, 1);
        nrm += __shfl_xor(nrm, 2);
        nrm += __shfl_xor(nrm, 4);
        half4v h = { (_Float16)(v.x * BSCALE), (_Float16)(v.y * BSCALE),
                     (_Float16)(v.z * BSCALE), (_Float16)(v.w * BSCALE) };
        *(half4v*)(Xth + row * DD + part * 4) = h;
        if (part == 0)
            c[row] = w[row] * __builtin_amdgcn_exp2f(-0.5f * LOG2E * nrm) * CENTER;
    } else {                             // ---- sum(w): 64 blocks
        int bid = b - 2176;
        float v = 0.f;
        for (int i = bid * 256 + threadIdx.x; i < NN; i += 64 * 256)
            v += w[i];
        #pragma unroll
        for (int o = 1; o < 64; o <<= 1) v += __shfl_xor(v, o);
        __shared__ float red[4];
        if ((threadIdx.x & 63) == 0) red[threadIdx.x >> 6] = v;
        __syncthreads();
        if (threadIdx.x == 0) atomicAdd(sumw, red[0] + red[1] + red[2] + red[3]);
    }
}

// Main kernel: per wave, 64 queries x strip of 512 train points, n-loop
// unrolled x2. Grid (QN/256, 128), block 256 = 4 waves. Identical skeleton
// to R4 (52.5 us, VGPR 68, no spill) with the fexp epilogue swapped in.
__global__ __launch_bounds__(256) void kde_main(
    const _Float16* __restrict__ Xh, const _Float16* __restrict__ Xth,
    const float* __restrict__ c, float* __restrict__ S) {
    const int lane   = threadIdx.x & 63;
    const int wave   = threadIdx.x >> 6;
    const int quad   = lane >> 4;
    const int l16    = lane & 15;
    const int m_base = blockIdx.x * 256 + wave * 64;
    const int n_beg  = blockIdx.y * 512;

    // A fragments: 4 tiles of 16 queries, resident for the whole strip.
    half8 a0 = *(const half8*)(Xh + (m_base +  0 + l16) * DD + quad * 8);
    half8 a1 = *(const half8*)(Xh + (m_base + 16 + l16) * DD + quad * 8);
    half8 a2 = *(const half8*)(Xh + (m_base + 32 + l16) * DD + quad * 8);
    half8 a3 = *(const half8*)(Xh + (m_base + 48 + l16) * DD + quad * 8);

    float s0[4][4] = {};
    float s1[4][4] = {};
    const floatx4 cbias = {BIAS_F, BIAS_F, BIAS_F, BIAS_F};

    const _Float16* bp = Xth + (size_t)(n_beg + l16) * DD + quad * 8;
    const float*    cp = c + n_beg + l16;

    for (int it = 0; it < 16; ++it) {
        half8 b0 = *(const half8*)bp;
        half8 b1 = *(const half8*)(bp + 16 * DD);
        float c0 = cp[0];
        float c1 = cp[16];
        bp += 32 * DD;
        cp += 32;

        // MFMA emits (g+127)*2^23 directly (bias via C operand).
        floatx4 g00 = __builtin_amdgcn_mfma_f32_16x16x32_f16(a0, b0, cbias, 0, 0, 0);
        floatx4 g10 = __builtin_amdgcn_mfma_f32_16x16x32_f16(a0, b1, cbias, 0, 0, 0);
        floatx4 g01 = __builtin_amdgcn_mfma_f32_16x16x32_f16(a1, b0, cbias, 0, 0, 0);
        floatx4 g11 = __builtin_amdgcn_mfma_f32_16x16x32_f16(a1, b1, cbias, 0, 0, 0);
        floatx4 g02 = __builtin_amdgcn_mfma_f32_16x16x32_f16(a2, b0, cbias, 0, 0, 0);
        floatx4 g12 = __builtin_amdgcn_mfma_f32_16x16x32_f16(a2, b1, cbias, 0, 0, 0);
        floatx4 g03 = __builtin_amdgcn_mfma_f32_16x16x32_f16(a3, b0, cbias, 0, 0, 0);
        floatx4 g13 = __builtin_amdgcn_mfma_f32_16x16x32_f16(a3, b1, cbias, 0, 0, 0);

        #pragma unroll
        for (int r = 0; r < 4; ++r) {
            s0[0][r] += c0 * fexp_term(g00[r]);
            s1[0][r] += c1 * fexp_term(g10[r]);
            s0[1][r] += c0 * fexp_term(g01[r]);
            s1[1][r] += c1 * fexp_term(g11[r]);
            s0[2][r] += c0 * fexp_term(g02[r]);
            s1[2][r] += c1 * fexp_term(g12[r]);
            s0[3][r] += c0 * fexp_term(g03[r]);
            s1[3][r] += c1 * fexp_term(g13[r]);
        }
    }

    // Reduce over the 16 columns (lanes sharing the same quad), then atomic.
    #pragma unroll
    for (int t = 0; t < 4; ++t) {
        #pragma unroll
        for (int r = 0; r < 4; ++r) {
            float v = (t == 0 ? s0[0][r] + s1[0][r] :
                       t == 1 ? s0[1][r] + s1[1][r] :
                       t == 2 ? s0[2][r] + s1[2][r] :
                                s0[3][r] + s1[3][r]);
            v += __shfl_xor(v, 1);
            v += __shfl_xor(v, 2);
            v += __shfl_xor(v, 4);
            v += __shfl_xor(v, 8);
            if (l16 == 0)
                atomicAdd(&S[m_base + t * 16 + quad * 4 + r], v);
        }
    }
}

__global__ void finalize(const float* __restrict__ S, const float* __restrict__ qn,
                         const float* __restrict__ sumw, float* __restrict__ out) {
    int i = blockIdx.x * blockDim.x + threadIdx.x;
    out[i] = logf(S[i]) - qn[i] - HALF_D_LOG_2PI - logf(*sumw);
}

extern "C" void kernel_launch(void* const* d_in, const int* in_sizes, int n_in,
                              void* d_out, int out_size, void* d_ws, size_t ws_size,
                              hipStream_t stream) {
    const float* X  = (const float*)d_in[0];
    const float* Xt = (const float*)d_in[1];
    const float* w  = (const float*)d_in[2];
    float* out = (float*)d_out;

    char* ws = (char*)d_ws;
    _Float16* Xh   = (_Float16*)(ws);
    _Float16* Xth  = (_Float16*)(ws + 262144);
    float*    c    = (float*)(ws + 4456448);
    float*    qn   = (float*)(ws + 4718592);
    float*    S    = (float*)(ws + 4734976);
    float*    sumw = (float*)(ws + 4751360);

    // Zero S + sumw (contiguous) — ws is poisoned 0xAA before each timed call.
    hipMemsetAsync(S, 0, QN * sizeof(float) + sizeof(float), stream);

    prep_all<<<2240, 256, 0, stream>>>(X, Xt, w, Xh, qn, Xth, c, sumw);
    kde_main<<<dim3(QN / 256, 128), 256, 0, stream>>>(Xh, Xth, c, S);
    finalize<<<QN / 256, 256, 0, stream>>>(S, qn, sumw, out);
}

// Round 7
// 111.558 us; speedup vs baseline: 2.2397x; 1.0623x over previous
//
#include <hip/hip_runtime.h>
#include <math.h>

// Problem constants (fixed by the reference): Q=4096 queries, N=65536 train, D=32.
#define QN 4096
#define NN 65536
#define DD 32

typedef __attribute__((ext_vector_type(8))) _Float16 half8;
typedef __attribute__((ext_vector_type(4))) _Float16 half4v;
typedef __attribute__((ext_vector_type(4))) float floatx4;

#define LOG2E 1.4426950408889634f
#define HALF_D_LOG_2PI 29.40603306254953f   // 16 * ln(2*pi)

// exp2-in-MFMA scaling: A = x*log2(e)*2^11, B = y*2^12, C = 127*2^23.
// MFMA emits v = (127 + x.y*log2e)*2^23 == the float bit pattern of
// 2^(x.y*log2e) under the linear-mantissa approximation. Per element:
// med3 clamp -> cvt_i32 -> fmac = 3 full-rate VALU ops. Validated R5/R6
// (absmax 0.25, identical to real exp2 -> error dominated by f16 rounding).
#define ASCALE 2954.6394357789634f   // log2(e) * 2048
#define BSCALE 4096.0f               // 2^12
#define BIAS_F 1065353216.0f         // 127 * 2^23
#define CAPF   1585446912.0f         // (127+62) * 2^23  (keeps cvt < INT_MAX)
#define CENTER 0.970656f             // centers the one-sided approx error

__device__ __forceinline__ float fexp_term(float v) {
    v = __builtin_amdgcn_fmed3f(v, 0.0f, CAPF);   // single v_med3_f32
    return __int_as_float((int)v);
}

// ---------------------------------------------------------------------------
// Workspace layout (bytes):
//   Xh    @ 0        : QN*DD*2 = 262144   (_Float16, X * ASCALE)
//   Xth   @ 262144   : NN*DD*2 = 4194304  (_Float16, X_train * BSCALE)
//   c     @ 4456448  : NN*4    = 262144   (CENTER * w_j * exp(-||y_j||^2/2))
//   qn    @ 4718592  : QN*4    = 16384    (||x_i||^2 / 2, nat units)
//   S     @ 4734976  : QN*4    = 16384    (zeroed by prep_all)
//   swp   @ 4751360  : 64*4    = 256      (per-block partial sums of w)
// Prefetch over-read: kde_main reads <= 64 B past Xth/c ends; both land in
// the adjacent ws regions (c/qn) -- in-bounds, values discarded.
// ---------------------------------------------------------------------------

// Fused prep: blocks [0,128) convert X (+ zero S), [128,2176) convert
// X_train + c, [2176,2240) reduce sum(w) into per-block partials.
// No fences, no cross-block protocol (R5 lesson: agent fences cost ~140us).
__global__ __launch_bounds__(256) void prep_all(
    const float* __restrict__ X, const float* __restrict__ Xt,
    const float* __restrict__ w, _Float16* __restrict__ Xh,
    float* __restrict__ qn, _Float16* __restrict__ Xth,
    float* __restrict__ c, float* __restrict__ S,
    float* __restrict__ swp) {
    const int b = blockIdx.x;
    if (b < 128) {                       // ---- prep X: QN rows, 8 lanes/row
        int tid  = b * 256 + threadIdx.x;
        int row  = tid >> 3;
        int part = tid & 7;
        const float4 v = ((const float4*)X)[row * 8 + part];
        float nrm = v.x * v.x + v.y * v.y + v.z * v.z + v.w * v.w;
        nrm += __shfl_xor(nrm, 1);
        nrm += __shfl_xor(nrm, 2);
        nrm += __shfl_xor(nrm, 4);
        half4v h = { (_Float16)(v.x * ASCALE), (_Float16)(v.y * ASCALE),
                     (_Float16)(v.z * ASCALE), (_Float16)(v.w * ASCALE) };
        *(half4v*)(Xh + row * DD + part * 4) = h;
        if (part == 0) qn[row] = 0.5f * nrm;
        if (tid < QN) S[tid] = 0.f;      // fused zeroing of S (R5-proven)
    } else if (b < 2176) {               // ---- prep X_train: NN rows
        int tid  = (b - 128) * 256 + threadIdx.x;
        int row  = tid >> 3;
        int part = tid & 7;
        const float4 v = ((const float4*)Xt)[row * 8 + part];
        float nrm = v.x * v.x + v.y * v.y + v.z * v.z + v.w * v.w;
        nrm += __shfl_xor(nrm, 1);
        nrm += __shfl_xor(nrm, 2);
        nrm += __shfl_xor(nrm, 4);
        half4v h = { (_Float16)(v.x * BSCALE), (_Float16)(v.y * BSCALE),
                     (_Float16)(v.z * BSCALE), (_Float16)(v.w * BSCALE) };
        *(half4v*)(Xth + row * DD + part * 4) = h;
        if (part == 0)
            c[row] = w[row] * __builtin_amdgcn_exp2f(-0.5f * LOG2E * nrm) * CENTER;
    } else {                             // ---- sum(w) partials: 64 blocks
        int bid = b - 2176;
        float v = 0.f;
        for (int i = bid * 256 + threadIdx.x; i < NN; i += 64 * 256)
            v += w[i];
        #pragma unroll
        for (int o = 1; o < 64; o <<= 1) v += __shfl_xor(v, o);
        __shared__ float red[4];
        if ((threadIdx.x & 63) == 0) red[threadIdx.x >> 6] = v;
        __syncthreads();
        if (threadIdx.x == 0) swp[bid] = red[0] + red[1] + red[2] + red[3];
    }
}

// Main kernel: per wave, 64 queries x strip of 512 train points, n-loop
// unrolled x2 with distance-1 register prefetch. 1-D grid of 2048 blocks,
// XCD-swizzled so each XCD owns 16 strips (512 KB of Xth -> L2-resident).
__global__ __launch_bounds__(256) void kde_main(
    const _Float16* __restrict__ Xh, const _Float16* __restrict__ Xth,
    const float* __restrict__ c, float* __restrict__ S) {
    const int lane   = threadIdx.x & 63;
    const int wave   = threadIdx.x >> 6;
    const int quad   = lane >> 4;
    const int l16    = lane & 15;

    // XCD swizzle: blocks with the same (b & 7) land on the same XCD
    // (round-robin heuristic); give them the same set of strips.
    const int b      = blockIdx.x;           // 0..2047
    const int xcd    = b & 7;
    const int slot   = b >> 3;               // 0..255
    const int qx     = slot & 15;            // query tile 0..15
    const int strip  = xcd + 8 * (slot >> 4);// 0..127, fixed per XCD class
    const int m_base = qx * 256 + wave * 64;
    const int n_beg  = strip * 512;

    // A fragments: 4 tiles of 16 queries, resident for the whole strip.
    half8 a0 = *(const half8*)(Xh + (m_base +  0 + l16) * DD + quad * 8);
    half8 a1 = *(const half8*)(Xh + (m_base + 16 + l16) * DD + quad * 8);
    half8 a2 = *(const half8*)(Xh + (m_base + 32 + l16) * DD + quad * 8);
    half8 a3 = *(const half8*)(Xh + (m_base + 48 + l16) * DD + quad * 8);

    float s0[4][4] = {};
    float s1[4][4] = {};
    const floatx4 cbias = {BIAS_F, BIAS_F, BIAS_F, BIAS_F};

    const _Float16* bp = Xth + (size_t)(n_beg + l16) * DD + quad * 8;
    const float*    cp = c + n_beg + l16;

    // Prologue loads for iteration 0.
    half8 b0 = *(const half8*)bp;
    half8 b1 = *(const half8*)(bp + 16 * DD);
    float c0 = cp[0];
    float c1 = cp[16];

    for (int it = 0; it < 16; ++it) {
        bp += 32 * DD;
        cp += 32;
        // Distance-1 prefetch: issued here, consumed next iteration --
        // the ~250-cy epilogue below hides the L2 latency.
        half8 nb0 = *(const half8*)bp;
        half8 nb1 = *(const half8*)(bp + 16 * DD);
        float nc0 = cp[0];
        float nc1 = cp[16];

        // MFMA emits (g+127)*2^23 directly (bias via C operand).
        floatx4 g00 = __builtin_amdgcn_mfma_f32_16x16x32_f16(a0, b0, cbias, 0, 0, 0);
        floatx4 g10 = __builtin_amdgcn_mfma_f32_16x16x32_f16(a0, b1, cbias, 0, 0, 0);
        floatx4 g01 = __builtin_amdgcn_mfma_f32_16x16x32_f16(a1, b0, cbias, 0, 0, 0);
        floatx4 g11 = __builtin_amdgcn_mfma_f32_16x16x32_f16(a1, b1, cbias, 0, 0, 0);
        floatx4 g02 = __builtin_amdgcn_mfma_f32_16x16x32_f16(a2, b0, cbias, 0, 0, 0);
        floatx4 g12 = __builtin_amdgcn_mfma_f32_16x16x32_f16(a2, b1, cbias, 0, 0, 0);
        floatx4 g03 = __builtin_amdgcn_mfma_f32_16x16x32_f16(a3, b0, cbias, 0, 0, 0);
        floatx4 g13 = __builtin_amdgcn_mfma_f32_16x16x32_f16(a3, b1, cbias, 0, 0, 0);

        #pragma unroll
        for (int r = 0; r < 4; ++r) {
            s0[0][r] += c0 * fexp_term(g00[r]);
            s1[0][r] += c1 * fexp_term(g10[r]);
            s0[1][r] += c0 * fexp_term(g01[r]);
            s1[1][r] += c1 * fexp_term(g11[r]);
            s0[2][r] += c0 * fexp_term(g02[r]);
            s1[2][r] += c1 * fexp_term(g12[r]);
            s0[3][r] += c0 * fexp_term(g03[r]);
            s1[3][r] += c1 * fexp_term(g13[r]);
        }

        b0 = nb0; b1 = nb1; c0 = nc0; c1 = nc1;
    }

    // Reduce over the 16 columns (lanes sharing the same quad), then atomic.
    #pragma unroll
    for (int t = 0; t < 4; ++t) {
        #pragma unroll
        for (int r = 0; r < 4; ++r) {
            float v = (t == 0 ? s0[0][r] + s1[0][r] :
                       t == 1 ? s0[1][r] + s1[1][r] :
                       t == 2 ? s0[2][r] + s1[2][r] :
                                s0[3][r] + s1[3][r]);
            v += __shfl_xor(v, 1);
            v += __shfl_xor(v, 2);
            v += __shfl_xor(v, 4);
            v += __shfl_xor(v, 8);
            if (l16 == 0)
                atomicAdd(&S[m_base + t * 16 + quad * 4 + r], v);
        }
    }
}

// Finalize: 16 blocks x 256 threads; sums the 64 w-partials via shuffle.
__global__ void finalize(const float* __restrict__ S, const float* __restrict__ qn,
                         const float* __restrict__ swp, float* __restrict__ out) {
    float pv = swp[threadIdx.x & 63];
    pv += __shfl_xor(pv, 1);
    pv += __shfl_xor(pv, 2);
    pv += __shfl_xor(pv, 4);
    pv += __shfl_xor(pv, 8);
    pv += __shfl_xor(pv, 16);
    pv += __shfl_xor(pv, 32);
    float lsw = logf(pv);
    int i = blockIdx.x * blockDim.x + threadIdx.x;
    out[i] = logf(S[i]) - qn[i] - HALF_D_LOG_2PI - lsw;
}

extern "C" void kernel_launch(void* const* d_in, const int* in_sizes, int n_in,
                              void* d_out, int out_size, void* d_ws, size_t ws_size,
                              hipStream_t stream) {
    const float* X  = (const float*)d_in[0];
    const float* Xt = (const float*)d_in[1];
    const float* w  = (const float*)d_in[2];
    float* out = (float*)d_out;

    char* ws = (char*)d_ws;
    _Float16* Xh   = (_Float16*)(ws);
    _Float16* Xth  = (_Float16*)(ws + 262144);
    float*    c    = (float*)(ws + 4456448);
    float*    qn   = (float*)(ws + 4718592);
    float*    S    = (float*)(ws + 4734976);
    float*    swp  = (float*)(ws + 4751360);

    prep_all<<<2240, 256, 0, stream>>>(X, Xt, w, Xh, qn, Xth, c, S, swp);
    kde_main<<<2048, 256, 0, stream>>>(Xh, Xth, c, S);
    finalize<<<QN / 256, 256, 0, stream>>>(S, qn, swp, out);
}